// Round 2
// baseline (788.626 us; speedup 1.0000x reference)
//
#include <hip/hip_runtime.h>
#include <stdint.h>

#define NN   8192
#define DIN  512
#define DOUT 512
#define ALPHA 0.2f

typedef float          floatx4  __attribute__((ext_vector_type(4)));
typedef short          shortx8  __attribute__((ext_vector_type(8)));
typedef unsigned short ushortx4 __attribute__((ext_vector_type(4)));
typedef int            intx4    __attribute__((ext_vector_type(4)));

__device__ inline unsigned short f2bf(float x) {
    union { float f; unsigned u; } v; v.f = x;
    return (unsigned short)((v.u + 0x7FFFu + ((v.u >> 16) & 1u)) >> 16);
}
__device__ inline unsigned encf(float x) {
    union { float f; unsigned u; } v; v.f = x;
    return (v.u & 0x80000000u) ? ~v.u : (v.u | 0x80000000u);
}
__device__ inline float decf(unsigned e) {
    union { float f; unsigned u; } v;
    v.u = (e & 0x80000000u) ? (e & 0x7FFFFFFFu) : ~e;
    return v.f;
}
__device__ inline float lrelu(float x) { return fmaxf(x, ALPHA * x); }

// ---------------------------------------------------------------------------
// Kernel T: WT[n][k] = bf16(W[k][n])   (512x512)
// ---------------------------------------------------------------------------
__global__ __launch_bounds__(256) void transpose_w(const float* __restrict__ W,
                                                   unsigned short* __restrict__ WT) {
    __shared__ float tile[32][33];
    const int t = threadIdx.x;
    const int x = t & 31, y = t >> 5;
    const int tr = (blockIdx.x >> 4) * 32, tc = (blockIdx.x & 15) * 32;
#pragma unroll
    for (int i = 0; i < 4; i++) {
        int r = y + i * 8;
        tile[r][x] = W[(size_t)(tr + r) * DOUT + tc + x];
    }
    __syncthreads();
#pragma unroll
    for (int i = 0; i < 4; i++) {
        int r = y + i * 8;
        WT[(size_t)(tc + r) * DIN + tr + x] = f2bf(tile[x][r]);
    }
}

// ---------------------------------------------------------------------------
// Kernel A: Wh = h @ W (bf16 MFMA). 512 blocks x 16 rows, 4 waves (16r x 128c).
// 2-stage register pipeline on h and WT. Also writes WhT (bf16, col-major),
// f1 = Wh@a1, f2 = Wh@a2, atomicMax of max(f2).
// ---------------------------------------------------------------------------
__global__ __launch_bounds__(256) void gemm_wh(
    const float* __restrict__ h, const unsigned short* __restrict__ WT,
    const float* __restrict__ a, unsigned short* __restrict__ WhT,
    float* __restrict__ f1, float* __restrict__ f2, unsigned* __restrict__ Menc)
{
    __shared__ float f1s[4][16], f2s[4][16];
    const int t = threadIdx.x;
    const int w = t >> 6, lane = t & 63, l15 = lane & 15, q = lane >> 4;
    const int r0 = blockIdx.x * 16;
    const int wc0 = w * 128;

    floatx4 acc[8];
    const floatx4 z4 = {0.f, 0.f, 0.f, 0.f};
#pragma unroll
    for (int j = 0; j < 8; j++) acc[j] = z4;

    const float* hp = &h[(size_t)(r0 + l15) * DIN + q * 8];
    const unsigned short* bp = &WT[(size_t)(wc0 + l15) * DIN + q * 8];

    floatx4 hA[2][2];
    shortx8 bB[2][8];
    hA[0][0] = *(const floatx4*)hp;
    hA[0][1] = *(const floatx4*)(hp + 4);
#pragma unroll
    for (int nt = 0; nt < 8; nt++)
        bB[0][nt] = *(const shortx8*)(bp + (size_t)nt * 16 * DIN);

#pragma unroll 2
    for (int it = 0; it < 16; ++it) {
        const int c = it & 1, n = c ^ 1;
        const int kn = ((it + 1) & 15) * 32;
        hA[n][0] = *(const floatx4*)(hp + kn);
        hA[n][1] = *(const floatx4*)(hp + kn + 4);
#pragma unroll
        for (int nt = 0; nt < 8; nt++)
            bB[n][nt] = *(const shortx8*)(bp + (size_t)nt * 16 * DIN + kn);

        shortx8 af;
#pragma unroll
        for (int j = 0; j < 8; j++)
            af[j] = (short)f2bf(hA[c][j >> 2][j & 3]);
#pragma unroll
        for (int nt = 0; nt < 8; nt++)
            acc[nt] = __builtin_amdgcn_mfma_f32_16x16x32_bf16(af, bB[c][nt], acc[nt], 0, 0, 0);
    }

    // epilogue
    float a1v[8], a2v[8];
#pragma unroll
    for (int nt = 0; nt < 8; nt++) {
        int col = wc0 + nt * 16 + l15;
        a1v[nt] = a[col];
        a2v[nt] = a[DOUT + col];
    }
#pragma unroll
    for (int nt = 0; nt < 8; nt++) {
        int col = wc0 + nt * 16 + l15;
        ushortx4 pk;
#pragma unroll
        for (int reg = 0; reg < 4; reg++) pk[reg] = f2bf(acc[nt][reg]);
        *(ushortx4*)&WhT[(size_t)col * NN + r0 + q * 4] = pk;
    }
    float s1a[4], s2a[4];
#pragma unroll
    for (int reg = 0; reg < 4; reg++) {
        float s1 = 0.f, s2 = 0.f;
#pragma unroll
        for (int nt = 0; nt < 8; nt++) {
            s1 += acc[nt][reg] * a1v[nt];
            s2 += acc[nt][reg] * a2v[nt];
        }
        s1 += __shfl_xor(s1, 1, 64); s2 += __shfl_xor(s2, 1, 64);
        s1 += __shfl_xor(s1, 2, 64); s2 += __shfl_xor(s2, 2, 64);
        s1 += __shfl_xor(s1, 4, 64); s2 += __shfl_xor(s2, 4, 64);
        s1 += __shfl_xor(s1, 8, 64); s2 += __shfl_xor(s2, 8, 64);
        s1a[reg] = s1; s2a[reg] = s2;
    }
    if (l15 == 0) {
#pragma unroll
        for (int reg = 0; reg < 4; reg++) {
            f1s[w][q * 4 + reg] = s1a[reg];
            f2s[w][q * 4 + reg] = s2a[reg];
        }
    }
    __syncthreads();
    if (t < 16) {
        float v1 = f1s[0][t] + f1s[1][t] + f1s[2][t] + f1s[3][t];
        float v2 = f2s[0][t] + f2s[1][t] + f2s[2][t] + f2s[3][t];
        f1[r0 + t] = v1;
        f2[r0 + t] = v2;
        float mx = v2;
        mx = fmaxf(mx, __shfl_xor(mx, 1, 64));
        mx = fmaxf(mx, __shfl_xor(mx, 2, 64));
        mx = fmaxf(mx, __shfl_xor(mx, 4, 64));
        mx = fmaxf(mx, __shfl_xor(mx, 8, 64));
        if (t == 0) atomicMax(Menc, encf(mx));
    }
}

// ---------------------------------------------------------------------------
// Kernel 2: barrier-free GAT aggregation. 256 blocks x 32 rows x 512 cols,
// 4 waves (each 32r x 128c). Each wave computes its p A-fragments DIRECTLY
// in registers (A[m=lane&15][k=q*8+j]) from adj/f1/f2 — no LDS, no barriers.
// adj prefetched 3 iters deep (4-stage rotation), B/f2 2-stage.
// p -> bf16 via truncating v_perm (uniform bias cancels in softmax ratio).
// m_i = lrelu(f1_i + max f2) upper-bounds every masked score (lrelu monotone).
// ---------------------------------------------------------------------------
__global__ __launch_bounds__(256) void gat_agg(
    const int* __restrict__ adj, const unsigned short* __restrict__ WhT,
    const float* __restrict__ f1, const float* __restrict__ f2,
    const unsigned* __restrict__ Menc, float* __restrict__ out)
{
    const int t = threadIdx.x;
    const int w = t >> 6, lane = t & 63, l15 = lane & 15, q = lane >> 4;
    const int r0 = blockIdx.x * 32;
    const int wc0 = w * 128;

    const float M = decf(*Menc);
    const float f1v0 = f1[r0 + l15];
    const float f1v1 = f1[r0 + 16 + l15];
    const float mi0 = lrelu(f1v0 + M);
    const float mi1 = lrelu(f1v1 + M);

    floatx4 acc[2][8];
    const floatx4 z4 = {0.f, 0.f, 0.f, 0.f};
#pragma unroll
    for (int i = 0; i < 2; i++)
#pragma unroll
        for (int j = 0; j < 8; j++) acc[i][j] = z4;
    float ls0 = 0.f, ls1 = 0.f;

    const int* ap0 = adj + (size_t)(r0 + l15) * NN + q * 8;
    const int* ap1 = ap0 + (size_t)16 * NN;
    const unsigned short* bp = WhT + (size_t)(wc0 + l15) * NN + q * 8;
    const float* fp = f2 + q * 8;

    intx4   adjA[4][4];   // [stage][m0lo,m0hi,m1lo,m1hi]
    shortx8 bfr[2][8];
    floatx4 f2f[2][2];

#pragma unroll
    for (int s = 0; s < 3; s++) {
        const int k = s * 32;
        adjA[s][0] = *(const intx4*)(ap0 + k);
        adjA[s][1] = *(const intx4*)(ap0 + k + 4);
        adjA[s][2] = *(const intx4*)(ap1 + k);
        adjA[s][3] = *(const intx4*)(ap1 + k + 4);
    }
#pragma unroll
    for (int nt = 0; nt < 8; nt++)
        bfr[0][nt] = *(const shortx8*)(bp + (size_t)nt * 16 * NN);
    f2f[0][0] = *(const floatx4*)fp;
    f2f[0][1] = *(const floatx4*)(fp + 4);

#pragma unroll 4
    for (int it = 0; it < 256; ++it) {
        const int c4 = it & 3, p4 = (it + 3) & 3;
        const int c2 = it & 1, n2 = c2 ^ 1;
        const int ka = ((it + 3) & 255) * 32;   // wraps harmlessly at the tail
        const int kb = ((it + 1) & 255) * 32;

        // prefetches (adj: 3 iters ahead -> HBM latency covered; B/f2: 1 ahead)
        adjA[p4][0] = *(const intx4*)(ap0 + ka);
        adjA[p4][1] = *(const intx4*)(ap0 + ka + 4);
        adjA[p4][2] = *(const intx4*)(ap1 + ka);
        adjA[p4][3] = *(const intx4*)(ap1 + ka + 4);
#pragma unroll
        for (int nt = 0; nt < 8; nt++)
            bfr[n2][nt] = *(const shortx8*)(bp + (size_t)nt * 16 * NN + kb);
        f2f[n2][0] = *(const floatx4*)(fp + kb);
        f2f[n2][1] = *(const floatx4*)(fp + kb + 4);

        // p fragments, directly in A-operand layout
        unsigned pb0[8], pb1[8];
#pragma unroll
        for (int j = 0; j < 8; j++) {
            const float fj = f2f[c2][j >> 2][j & 3];
            const int a0 = (j < 4) ? adjA[c4][0][j & 3] : adjA[c4][1][j & 3];
            const int a1 = (j < 4) ? adjA[c4][2][j & 3] : adjA[c4][3][j & 3];
            float e0 = f1v0 + fj;
            float p0 = __expf(lrelu(e0) - mi0);
            p0 = a0 ? p0 : 0.f;
            ls0 += p0;
            pb0[j] = __float_as_uint(p0);
            float e1 = f1v1 + fj;
            float p1 = __expf(lrelu(e1) - mi1);
            p1 = a1 ? p1 : 0.f;
            ls1 += p1;
            pb1[j] = __float_as_uint(p1);
        }
        union { unsigned u[4]; shortx8 v; } u0, u1;
#pragma unroll
        for (int j = 0; j < 4; j++) {
            u0.u[j] = __builtin_amdgcn_perm(pb0[2 * j + 1], pb0[2 * j], 0x07060302u);
            u1.u[j] = __builtin_amdgcn_perm(pb1[2 * j + 1], pb1[2 * j], 0x07060302u);
        }
        const shortx8 af0 = u0.v, af1 = u1.v;

#pragma unroll
        for (int nt = 0; nt < 8; nt++) {
            acc[0][nt] = __builtin_amdgcn_mfma_f32_16x16x32_bf16(af0, bfr[c2][nt], acc[0][nt], 0, 0, 0);
            acc[1][nt] = __builtin_amdgcn_mfma_f32_16x16x32_bf16(af1, bfr[c2][nt], acc[1][nt], 0, 0, 0);
        }
    }

    // row sums: reduce over q (lanes l15, l15+16, l15+32, l15+48)
    ls0 += __shfl_xor(ls0, 16, 64);
    ls0 += __shfl_xor(ls0, 32, 64);
    ls1 += __shfl_xor(ls1, 16, 64);
    ls1 += __shfl_xor(ls1, 32, 64);
    const float inv0 = 1.f / ls0;   // reciprocal for row l15
    const float inv1 = 1.f / ls1;   // reciprocal for row 16 + l15

    // epilogue: normalize + ELU + store (C-layout: row = q*4+reg, col = l15)
#pragma unroll
    for (int reg = 0; reg < 4; reg++) {
        const int rl = q * 4 + reg;
        const float iv0 = __shfl(inv0, rl, 64);
        const float iv1 = __shfl(inv1, rl, 64);
#pragma unroll
        for (int nt = 0; nt < 8; nt++) {
            const int col = wc0 + nt * 16 + l15;
            float v0 = acc[0][nt][reg] * iv0;
            float v1 = acc[1][nt][reg] * iv1;
            out[(size_t)(r0 + rl) * DOUT + col]      = (v0 > 0.f) ? v0 : (__expf(v0) - 1.f);
            out[(size_t)(r0 + 16 + rl) * DOUT + col] = (v1 > 0.f) ? v1 : (__expf(v1) - 1.f);
        }
    }
}

// ---------------------------------------------------------------------------
extern "C" void kernel_launch(void* const* d_in, const int* in_sizes, int n_in,
                              void* d_out, int out_size, void* d_ws, size_t ws_size,
                              hipStream_t stream) {
    const float* h   = (const float*)d_in[0];
    const int*   adj = (const int*)d_in[1];
    const float* W   = (const float*)d_in[2];
    const float* a   = (const float*)d_in[3];
    float* out = (float*)d_out;

    char* ws = (char*)d_ws;
    unsigned short* WT   = (unsigned short*)ws;                        // 512 KB
    unsigned short* WhT  = (unsigned short*)(ws + 524288);             // 8 MB
    float*          f1   = (float*)(ws + 524288 + 8388608);            // 32 KB
    float*          f2   = (float*)(ws + 524288 + 8388608 + 32768);    // 32 KB
    unsigned*       Menc = (unsigned*)(ws + 524288 + 8388608 + 65536); // 4 B

    hipMemsetAsync(Menc, 0, 4, stream);
    transpose_w<<<256, 256, 0, stream>>>(W, WT);
    gemm_wh<<<512, 256, 0, stream>>>(h, WT, a, WhT, f1, f2, Menc);
    gat_agg<<<256, 256, 0, stream>>>(adj, WhT, f1, f2, Menc, out);
}